// Round 1
// baseline (131.660 us; speedup 1.0000x reference)
//
#include <hip/hip_runtime.h>

#define NN 192
#define YCHUNK 8
#define BZ 4

// Load row values v[0..5] = row[x0-1 .. x0+4] with edge clamping on x.
// Row base is 16B-aligned (x0 multiple of 4, row stride 192 floats).
__device__ __forceinline__ void load_row(const float* __restrict__ row, int x0, float v[6]) {
    const float4 c = *reinterpret_cast<const float4*>(row + x0);
    v[1] = c.x; v[2] = c.y; v[3] = c.z; v[4] = c.w;
    v[0] = row[(x0 == 0) ? 0 : (x0 - 1)];
    v[5] = row[(x0 + 4 > NN - 1) ? (NN - 1) : (x0 + 4)];
}

// For one gy: load the 3 rows (dz = -1,0,+1), fold into:
//   sa[i] = sum_dz (r[x+1]-r[x-1])          (for Ix)
//   sb[i] = sum_dz (r[x-1]+r[x]+r[x+1])     (for Iy)
//   tb[i] = (x-box at dz=+1) - (x-box at dz=-1)   (for Iz)
__device__ __forceinline__ void load_slot(const float* __restrict__ A,
                                          int bm, int b0, int bp, int x0,
                                          float sa[4], float sb[4], float tb[4]) {
    float vm[6], v0[6], vp[6];
    load_row(A + bm, x0, vm);
    load_row(A + b0, x0, v0);
    load_row(A + bp, x0, vp);
#pragma unroll
    for (int i = 0; i < 4; ++i) {
        const float am = vm[i + 2] - vm[i];
        const float a0 = v0[i + 2] - v0[i];
        const float ap = vp[i + 2] - vp[i];
        const float bmv = vm[i] + vm[i + 1] + vm[i + 2];
        const float b0v = v0[i] + v0[i + 1] + v0[i + 2];
        const float bpv = vp[i] + vp[i + 1] + vp[i + 2];
        sa[i] = am + a0 + ap;
        sb[i] = bmv + b0v + bpv;
        tb[i] = bpv - bmv;
    }
}

// Raw (un-halved) gradients: rawG = 2*trueG. The 0.5^2 factors cancel in
// ngf if EPS^2 (0.01) is replaced by 4*EPS^2 = 0.04:
//   ngf = dot^2 / ((|gI|^2 + 0.04) * (|gJ|^2 + 0.04))   with raw sums.
__global__ __launch_bounds__(192) void ngf_kernel(const float* __restrict__ I,
                                                  const float* __restrict__ J,
                                                  const float* __restrict__ M,
                                                  float* __restrict__ out) {
    const int xg = threadIdx.x;       // 0..47 -> 4-wide x group
    const int x0 = xg * 4;
    const int z = blockIdx.y * BZ + threadIdx.y;
    const int ybase = blockIdx.x * YCHUNK;

    const int gzm = (z == 0) ? 0 : z - 1;
    const int gzp = (z == NN - 1) ? (NN - 1) : z + 1;
    const int zbm = gzm * NN, zb0 = z * NN, zbp = gzp * NN;

    float saI[3][4], sbI[3][4], tbI[3][4];
    float saJ[3][4], sbJ[3][4], tbJ[3][4];

    // Seed rotating slots: slot0 <- gy = ybase-1 (clamped), slot1 <- gy = ybase
    {
        const int gy = (ybase == 0) ? 0 : ybase - 1;
        load_slot(I, (zbm + gy) * NN, (zb0 + gy) * NN, (zbp + gy) * NN, x0,
                  saI[0], sbI[0], tbI[0]);
        load_slot(J, (zbm + gy) * NN, (zb0 + gy) * NN, (zbp + gy) * NN, x0,
                  saJ[0], sbJ[0], tbJ[0]);
        load_slot(I, (zbm + ybase) * NN, (zb0 + ybase) * NN, (zbp + ybase) * NN, x0,
                  saI[1], sbI[1], tbI[1]);
        load_slot(J, (zbm + ybase) * NN, (zb0 + ybase) * NN, (zbp + ybase) * NN, x0,
                  saJ[1], sbJ[1], tbJ[1]);
    }

    float acc = 0.0f;
#pragma unroll
    for (int yy = 0; yy < YCHUNK; ++yy) {
        const int y = ybase + yy;
        const int gyp = (y == NN - 1) ? (NN - 1) : y + 1;
        const int s0 = yy % 3, s1 = (yy + 1) % 3, s2 = (yy + 2) % 3;
        load_slot(I, (zbm + gyp) * NN, (zb0 + gyp) * NN, (zbp + gyp) * NN, x0,
                  saI[s2], sbI[s2], tbI[s2]);
        load_slot(J, (zbm + gyp) * NN, (zb0 + gyp) * NN, (zbp + gyp) * NN, x0,
                  saJ[s2], sbJ[s2], tbJ[s2]);
        const float4 m4 = *reinterpret_cast<const float4*>(M + (zb0 + y) * NN + x0);
        const float mm[4] = {m4.x, m4.y, m4.z, m4.w};
#pragma unroll
        for (int i = 0; i < 4; ++i) {
            const float Ix = saI[s0][i] + saI[s1][i] + saI[s2][i];
            const float Iy = sbI[s2][i] - sbI[s0][i];
            const float Iz = tbI[s0][i] + tbI[s1][i] + tbI[s2][i];
            const float Jx = saJ[s0][i] + saJ[s1][i] + saJ[s2][i];
            const float Jy = sbJ[s2][i] - sbJ[s0][i];
            const float Jz = tbJ[s0][i] + tbJ[s1][i] + tbJ[s2][i];
            const float imag = Ix * Ix + Iy * Iy + Iz * Iz + 0.04f;
            const float jmag = Jx * Jx + Jy * Jy + Jz * Jz + 0.04f;
            const float dot = Ix * Jx + Iy * Jy + Iz * Jz;
            const float ngf = (dot * dot) / (imag * jmag);
            acc += (1.0f - ngf) * mm[i];
        }
    }

    // mean scaling, then wave -> block -> global reduction
    acc *= (1.0f / ((float)NN * (float)NN * (float)NN));
#pragma unroll
    for (int off = 32; off > 0; off >>= 1)
        acc += __shfl_down(acc, off, 64);

    __shared__ float red[3];
    const int flat = threadIdx.y * 48 + threadIdx.x;
    if ((flat & 63) == 0) red[flat >> 6] = acc;
    __syncthreads();
    if (flat == 0) atomicAdd(out, red[0] + red[1] + red[2]);
}

extern "C" void kernel_launch(void* const* d_in, const int* in_sizes, int n_in,
                              void* d_out, int out_size, void* d_ws, size_t ws_size,
                              hipStream_t stream) {
    const float* I = (const float*)d_in[0];
    const float* J = (const float*)d_in[1];
    const float* M = (const float*)d_in[2];
    float* out = (float*)d_out;

    // d_out is poisoned before every launch; zero it for the atomic accumulate.
    hipMemsetAsync(d_out, 0, sizeof(float), stream);

    dim3 block(48, BZ);               // 192 threads = 3 waves
    dim3 grid(NN / YCHUNK, NN / BZ);  // (24, 48) = 1152 blocks
    ngf_kernel<<<grid, block, 0, stream>>>(I, J, M, out);
}